// Round 19
// baseline (230.591 us; speedup 1.0000x reference)
//
#include <hip/hip_runtime.h>
#include <hip/hip_bf16.h>

typedef __attribute__((ext_vector_type(8))) short bf16x8;
typedef __attribute__((ext_vector_type(4))) float f32x4;
typedef unsigned short ushort_t;

#define S_LEN 2048
#define DMODEL 1024
#define NORM_F 0.125f

__device__ __forceinline__ short f2b(float x) {
  union { float f; unsigned u; } c; c.f = x;
  unsigned r = (c.u + 0x7FFFu + ((c.u >> 16) & 1u)) >> 16;
  return (short)r;
}
__device__ __forceinline__ float b2f(ushort_t u) {
  union { unsigned u; float f; } c; c.u = ((unsigned)u) << 16; return c.f;
}
__device__ __forceinline__ unsigned cvtpk(float lo, float hi) {
  unsigned r;
  asm volatile("v_cvt_pk_bf16_f32 %0, %1, %2" : "=v"(r) : "v"(lo), "v"(hi));
  return r;
}
__device__ __forceinline__ uint4 pack8(float4 a, float4 b) {
  union { ushort_t us[8]; uint4 v; } o;
  o.us[0] = (ushort_t)f2b(a.x); o.us[1] = (ushort_t)f2b(a.y);
  o.us[2] = (ushort_t)f2b(a.z); o.us[3] = (ushort_t)f2b(a.w);
  o.us[4] = (ushort_t)f2b(b.x); o.us[5] = (ushort_t)f2b(b.y);
  o.us[6] = (ushort_t)f2b(b.z); o.us[7] = (ushort_t)f2b(b.w);
  return o.v;
}

// ---------------------------------------------------------------------------
// Segment bits, packed: segw[b*64 + (i>>5)] bit (i&31) = seg id of (b, i).
// ---------------------------------------------------------------------------
__global__ void seg_extract_kernel(const unsigned int* __restrict__ seg_raw,
                                   unsigned* __restrict__ segw) {
  __shared__ int bad_int, bad_flt;
  int tid = threadIdx.x;
  if (tid == 0) { bad_int = 0; bad_flt = 0; }
  __syncthreads();
  for (int i = tid; i < 2048; i += 256) {
    unsigned v = seg_raw[i];
    if (v > 1u) atomicOr(&bad_int, 1);
    if (v != 0u && v != 0x3F800000u) atomicOr(&bad_flt, 1);
  }
  __syncthreads();
  int mode = bad_int ? (bad_flt ? 2 : 1) : 0;
  const unsigned char* u8 = (const unsigned char*)seg_raw;
  int P = blockIdx.x * 256 + tid;       // [0, 4096)
  int b = P >> 11, i = P & 2047;
  size_t off = (size_t)b * S_LEN * S_LEN + i;
  int bit;
  if (mode == 0)      bit = (int)(seg_raw[off] & 1u);
  else if (mode == 1) bit = (seg_raw[off] != 0u) ? 1 : 0;
  else                bit = (int)(u8[off] & 1u);
  unsigned long long mk = __ballot(bit);
  if ((tid & 63) == 0) {
    segw[P >> 5] = (unsigned)mk;
    segw[(P >> 5) + 1] = (unsigned)(mk >> 32);
  }
}

// ---------------------------------------------------------------------------
// Weight transpose+convert: W fp32 [1024 k][1024 n] -> Wt bf16 [n][k]
// ---------------------------------------------------------------------------
__global__ __launch_bounds__(256) void convT_kernel(
    const float* __restrict__ s0, const float* __restrict__ s1,
    const float* __restrict__ s2, const float* __restrict__ s3,
    const float* __restrict__ s4,
    ushort_t* __restrict__ d0, ushort_t* __restrict__ d1,
    ushort_t* __restrict__ d2, ushort_t* __restrict__ d3,
    ushort_t* __restrict__ d4) {
  int z = blockIdx.z;
  const float* src = z == 0 ? s0 : z == 1 ? s1 : z == 2 ? s2 : z == 3 ? s3 : s4;
  ushort_t* dst = z == 0 ? d0 : z == 1 ? d1 : z == 2 ? d2 : z == 3 ? d3 : d4;
  __shared__ float Tl[64][68];
  int tid = threadIdx.x;
  int k0 = blockIdx.x * 64, n0 = blockIdx.y * 64;
#pragma unroll
  for (int it = 0; it < 4; ++it) {
    int idx = tid + it * 256;
    int r = idx >> 4, c4 = (idx & 15) * 4;
    *(float4*)&Tl[r][c4] = *(const float4*)(src + (size_t)(k0 + r) * 1024 + n0 + c4);
  }
  __syncthreads();
#pragma unroll
  for (int it = 0; it < 2; ++it) {
    int idx = tid + it * 256;
    int nn = idx >> 3, kc = idx & 7;
    union { ushort_t us[8]; uint4 v; } o;
#pragma unroll
    for (int e = 0; e < 8; ++e) o.us[e] = (ushort_t)f2b(Tl[kc * 8 + e][nn]);
    *(uint4*)(dst + (size_t)(n0 + nn) * 1024 + k0 + kc * 8) = o.v;
  }
}

// ---------------------------------------------------------------------------
// Batched projection GEMM over fp32 activations (in-register bf16 convert):
// blockIdx.z selects {q,k,v,pe}. z==0 epilogue fuses qprep.
// ---------------------------------------------------------------------------
__global__ __launch_bounds__(256) void gemm4_kernel(
    const float* __restrict__ a0, const float* __restrict__ a1,
    const float* __restrict__ a2, const float* __restrict__ a3,
    const ushort_t* __restrict__ w0, const ushort_t* __restrict__ w1,
    const ushort_t* __restrict__ w2, const ushort_t* __restrict__ w3,
    const float* __restrict__ kb, const float* __restrict__ vb,
    const float* __restrict__ rwb, const float* __restrict__ rrb,
    const float* __restrict__ rsb, const float* __restrict__ sem,
    ushort_t* __restrict__ qwb, ushort_t* __restrict__ qrb,
    float2* __restrict__ sbp,
    ushort_t* __restrict__ c1, ushort_t* __restrict__ c2,
    ushort_t* __restrict__ c3) {
  const int z = blockIdx.z;
  const float* A     = z == 0 ? a0 : z == 1 ? a1 : z == 2 ? a2 : a3;
  const ushort_t* Wt = z == 0 ? w0 : z == 1 ? w1 : z == 2 ? w2 : w3;

  __shared__ short A_lds[128][40];
  __shared__ short B_lds[128][40];
  const int tid = threadIdx.x;
  const int wave = tid >> 6, lane = tid & 63;
  const int r16 = lane & 15, g = lane >> 4;
  const int wm = wave >> 1, wn = wave & 1;
  const int m0 = blockIdx.x * 128, n0 = blockIdx.y * 128;
  const int sr = tid >> 2, sseg = (tid & 3) * 8;
  f32x4 acc[4][4] = {};
  float4 fa0a = *(const float4*)(A + (size_t)(m0 + sr) * 1024 + sseg);
  float4 fa0b = *(const float4*)(A + (size_t)(m0 + sr) * 1024 + sseg + 4);
  float4 fa1a = *(const float4*)(A + (size_t)(m0 + 64 + sr) * 1024 + sseg);
  float4 fa1b = *(const float4*)(A + (size_t)(m0 + 64 + sr) * 1024 + sseg + 4);
  uint4 rb0 = *(const uint4*)(Wt + (size_t)(n0 + sr) * 1024 + sseg);
  uint4 rb1 = *(const uint4*)(Wt + (size_t)(n0 + 64 + sr) * 1024 + sseg);
  for (int k0 = 0; k0 < 1024; k0 += 32) {
    *(uint4*)&A_lds[sr][sseg] = pack8(fa0a, fa0b);
    *(uint4*)&A_lds[64 + sr][sseg] = pack8(fa1a, fa1b);
    *(uint4*)&B_lds[sr][sseg] = rb0;
    *(uint4*)&B_lds[64 + sr][sseg] = rb1;
    __syncthreads();
    if (k0 + 32 < 1024) {
      fa0a = *(const float4*)(A + (size_t)(m0 + sr) * 1024 + k0 + 32 + sseg);
      fa0b = *(const float4*)(A + (size_t)(m0 + sr) * 1024 + k0 + 32 + sseg + 4);
      fa1a = *(const float4*)(A + (size_t)(m0 + 64 + sr) * 1024 + k0 + 32 + sseg);
      fa1b = *(const float4*)(A + (size_t)(m0 + 64 + sr) * 1024 + k0 + 32 + sseg + 4);
      rb0 = *(const uint4*)(Wt + (size_t)(n0 + sr) * 1024 + k0 + 32 + sseg);
      rb1 = *(const uint4*)(Wt + (size_t)(n0 + 64 + sr) * 1024 + k0 + 32 + sseg);
    }
    bf16x8 af[4], bfr[4];
#pragma unroll
    for (int fm = 0; fm < 4; ++fm)
      af[fm] = *(const bf16x8*)&A_lds[wm * 64 + fm * 16 + r16][g * 8];
#pragma unroll
    for (int fn = 0; fn < 4; ++fn)
      bfr[fn] = *(const bf16x8*)&B_lds[wn * 64 + fn * 16 + r16][g * 8];
#pragma unroll
    for (int fm = 0; fm < 4; ++fm)
#pragma unroll
      for (int fn = 0; fn < 4; ++fn)
        acc[fm][fn] = __builtin_amdgcn_mfma_f32_16x16x32_bf16(af[fm], bfr[fn], acc[fm][fn], 0, 0, 0);
    __syncthreads();
  }

  if (z == 0) {
    // fused qprep epilogue: this wave's 64-col half is one full head.
    float rwbN[4], rrbN[4], rsbN[4], s0c[4], s1c[4];
#pragma unroll
    for (int fn = 0; fn < 4; ++fn) {
      int col = n0 + wn * 64 + fn * 16 + r16;
      rwbN[fn] = rwb[col] * NORM_F;
      rrbN[fn] = rrb[col] * NORM_F;
      rsbN[fn] = rsb[col] * NORM_F;
      s0c[fn] = sem[col];
      s1c[fn] = sem[1024 + col];
    }
    const int nI = (n0 >> 6) + wn;   // head index 0..15
#pragma unroll
    for (int fm = 0; fm < 4; ++fm)
#pragma unroll
      for (int rr = 0; rr < 4; ++rr) {
        int row = m0 + wm * 64 + fm * 16 + g * 4 + rr;
        float p0 = 0.f, p1 = 0.f;
#pragma unroll
        for (int fn = 0; fn < 4; ++fn) {
          float vv = acc[fm][fn][rr] * NORM_F;
          size_t off = (size_t)row * 1024 + n0 + wn * 64 + fn * 16 + r16;
          qwb[off] = (ushort_t)f2b(vv + rwbN[fn]);
          qrb[off] = (ushort_t)f2b(vv + rrbN[fn]);
          float qs = vv + rsbN[fn];
          p0 += qs * s0c[fn];
          p1 += qs * s1c[fn];
        }
        p0 += __shfl_xor(p0, 1); p0 += __shfl_xor(p0, 2);
        p0 += __shfl_xor(p0, 4); p0 += __shfl_xor(p0, 8);
        p1 += __shfl_xor(p1, 1); p1 += __shfl_xor(p1, 2);
        p1 += __shfl_xor(p1, 4); p1 += __shfl_xor(p1, 8);
        if (r16 == 0) {
          int bI = row >> 11, iI = row & 2047;
          sbp[((size_t)bI * 16 + nI) * 2048 + iI] = make_float2(p0, p1);
        }
      }
  } else {
    const float* bias = z == 1 ? kb : z == 2 ? vb : (const float*)nullptr;
    ushort_t* C = z == 1 ? c1 : z == 2 ? c2 : c3;
    float bv[4];
#pragma unroll
    for (int fn = 0; fn < 4; ++fn)
      bv[fn] = bias ? bias[n0 + wn * 64 + fn * 16 + r16] : 0.f;
#pragma unroll
    for (int fm = 0; fm < 4; ++fm)
#pragma unroll
      for (int fn = 0; fn < 4; ++fn)
#pragma unroll
        for (int rr = 0; rr < 4; ++rr) {
          float vv = acc[fm][fn][rr] + bv[fn];
          size_t off = (size_t)(m0 + wm * 64 + fm * 16 + g * 4 + rr) * 1024 +
                       n0 + wn * 64 + fn * 16 + r16;
          C[off] = (ushort_t)f2b(vv);
        }
  }
}

// ---------------------------------------------------------------------------
// Post-projection GEMM, 64x128 tile (512 blocks = 2/CU), fp32 out.
// ---------------------------------------------------------------------------
__global__ __launch_bounds__(256) void gemm_post_kernel(
    const ushort_t* __restrict__ A, const ushort_t* __restrict__ Wt,
    const float* __restrict__ bias, float* __restrict__ C) {
  __shared__ short A_lds[64][40];
  __shared__ short B_lds[128][40];
  const int tid = threadIdx.x;
  const int wave = tid >> 6, lane = tid & 63;
  const int r16 = lane & 15, g = lane >> 4;
  const int wm = wave >> 1, wn = wave & 1;
  const int m0 = blockIdx.x * 64, n0 = blockIdx.y * 128;
  const int sr = tid >> 2, sseg = (tid & 3) * 8;
  f32x4 acc[2][4] = {};
  uint4 ra0 = *(const uint4*)(A + (size_t)(m0 + sr) * 1024 + sseg);
  uint4 rb0 = *(const uint4*)(Wt + (size_t)(n0 + sr) * 1024 + sseg);
  uint4 rb1 = *(const uint4*)(Wt + (size_t)(n0 + 64 + sr) * 1024 + sseg);
  for (int k0 = 0; k0 < 1024; k0 += 32) {
    *(uint4*)&A_lds[sr][sseg] = ra0;
    *(uint4*)&B_lds[sr][sseg] = rb0;
    *(uint4*)&B_lds[64 + sr][sseg] = rb1;
    __syncthreads();
    if (k0 + 32 < 1024) {
      ra0 = *(const uint4*)(A + (size_t)(m0 + sr) * 1024 + k0 + 32 + sseg);
      rb0 = *(const uint4*)(Wt + (size_t)(n0 + sr) * 1024 + k0 + 32 + sseg);
      rb1 = *(const uint4*)(Wt + (size_t)(n0 + 64 + sr) * 1024 + k0 + 32 + sseg);
    }
    bf16x8 af[2], bfr[4];
#pragma unroll
    for (int fm = 0; fm < 2; ++fm)
      af[fm] = *(const bf16x8*)&A_lds[wm * 32 + fm * 16 + r16][g * 8];
#pragma unroll
    for (int fn = 0; fn < 4; ++fn)
      bfr[fn] = *(const bf16x8*)&B_lds[wn * 64 + fn * 16 + r16][g * 8];
#pragma unroll
    for (int fm = 0; fm < 2; ++fm)
#pragma unroll
      for (int fn = 0; fn < 4; ++fn)
        acc[fm][fn] = __builtin_amdgcn_mfma_f32_16x16x32_bf16(af[fm], bfr[fn], acc[fm][fn], 0, 0, 0);
    __syncthreads();
  }
  float bv[4];
#pragma unroll
  for (int fn = 0; fn < 4; ++fn)
    bv[fn] = bias ? bias[n0 + wn * 64 + fn * 16 + r16] : 0.f;
#pragma unroll
  for (int fm = 0; fm < 2; ++fm)
#pragma unroll
    for (int fn = 0; fn < 4; ++fn)
#pragma unroll
      for (int rr = 0; rr < 4; ++rr) {
        size_t off = (size_t)(m0 + wm * 32 + fm * 16 + g * 4 + rr) * 1024 +
                     n0 + wn * 64 + fn * 16 + r16;
        C[off] = acc[fm][fn][rr] + bv[fn];
      }
}

// ---------------------------------------------------------------------------
// Fused causal relative attention: R18 structure with SINGLE barrier/tile.
// K double-buffered, V double-buffered, R 192-row (3-half) circular buffer:
// every commit targets a region last read by tile t-1, whose reads completed
// before this tile's loop-top barrier -> barrier B deleted.
// ---------------------------------------------------------------------------
__global__ __launch_bounds__(256) void attn_kernel(
    const ushort_t* __restrict__ qwb, const ushort_t* __restrict__ qrb,
    const ushort_t* __restrict__ khb, const ushort_t* __restrict__ vhb,
    const ushort_t* __restrict__ rhb, const float2* __restrict__ sbp,
    const unsigned* __restrict__ segw, ushort_t* __restrict__ opart,
    float* __restrict__ ml) {
  __shared__ short Klds[2][64][64];
  __shared__ short Rlds[192][64];
  __shared__ short VsT[2][64][72];
  __shared__ short SP[4][1344];

  const int tid = threadIdx.x;
  const int w = tid >> 6, lane = tid & 63;
  const int r16 = lane & 15, g = lane >> 4;
  // XCD swizzle: lin -> (group g in [0,32), j in [0,64)); XCD = lin % 8 = g % 8
  const int lin = (int)blockIdx.x;
  const int grp = (lin & 7) + ((lin >> 9) << 3);
  const int j = (lin >> 3) & 63;
  const int x = 31 - (j >> 1);
  const int hx = j & 1;
  const int i0 = x * 64;
  const int nh = (x + 2) >> 1;
  const int tbeg = hx ? nh : 0;
  const int tend = hx ? (x + 1) : nh;
  const int n = grp & 15, b = grp >> 4;
  const int BNS = 65536;
  const int rowbase = (b * 16 + n) * 2048 + i0;

  if (tbeg >= tend) {  // empty half (only hx==1, x==0)
    const int il0 = w * 16 + g * 4;
#pragma unroll
    for (int rr = 0; rr < 4; ++rr) {
#pragma unroll
      for (int s = 0; s < 4; ++s)
        opart[(size_t)(BNS + rowbase + il0 + rr) * 64 + s * 16 + r16] = 0;
      if (r16 == 0) {
        ml[2 * BNS + rowbase + il0 + rr] = -1e30f;
        ml[3 * BNS + rowbase + il0 + rr] = 0.f;
      }
    }
    return;
  }

  short* SPw = &SP[w][0];
  const int srow = tid >> 3, sg8 = (tid & 7) * 8;

  // per-lane persistent state (q-row = r16 within this wave's 16 rows)
  const int qrow = i0 + w * 16 + r16;
  const ushort_t* qwp = qwb + (size_t)(b * S_LEN + qrow) * DMODEL + n * 64 + g * 8;
  const ushort_t* qrp = qrb + (size_t)(b * S_LEN + qrow) * DMODEL + n * 64 + g * 8;
  bf16x8 qw[2], qr[2];
  qw[0] = *(const bf16x8*)qwp;  qw[1] = *(const bf16x8*)(qwp + 32);
  qr[0] = *(const bf16x8*)qrp;  qr[1] = *(const bf16x8*)(qrp + 32);
  float2 sbv = sbp[((size_t)b * 16 + n) * 2048 + qrow];
  const float sb0 = sbv.x, sb1 = sbv.y;
  const int ai = (segw[b * 64 + (qrow >> 5)] >> (qrow & 31)) & 1;
  const int iw0 = i0 + w * 16;

  // prologue: stage tile tbeg (K buf0, R phys [0,128) at A0m=0, V buf0)
  {
    const int j0 = tbeg * 64;
    const int W0 = 2048 + j0 - i0 - 63;
#pragma unroll
    for (int it = 0; it < 2; ++it) {
      int qk = tid + it * 256, row = qk >> 3, cl = qk & 7;
      uint4 kv = *(const uint4*)(khb + (size_t)(b * S_LEN + j0 + row) * DMODEL + n * 64 + cl * 8);
      *(uint4*)&Klds[0][row][(cl ^ (row & 7)) * 8] = kv;
    }
#pragma unroll
    for (int it = 0; it < 4; ++it) {
      int qk = tid + it * 256, row = qk >> 3, cl = qk & 7;
      uint4 rv = *(const uint4*)(rhb + (size_t)(W0 + row) * DMODEL + n * 64 + cl * 8);
      *(uint4*)&Rlds[row][(cl ^ (row & 7)) * 8] = rv;
    }
#pragma unroll
    for (int it = 0; it < 2; ++it) {
      int jj = srow + it * 32;
      union { uint4 v; ushort_t us[8]; } vv;
      vv.v = *(const uint4*)(vhb + (size_t)(b * S_LEN + j0 + jj) * DMODEL + n * 64 + sg8);
#pragma unroll
      for (int e = 0; e < 8; ++e) {
        int hh = sg8 + e;
        VsT[0][hh][((jj >> 3) ^ (hh >> 3)) * 8 + (jj & 7)] = (short)vv.us[e];
      }
    }
  }

  float m_r = -1e30f, l_r = 0.f;
  f32x4 o[4] = {};
  int A0m = 0;   // circular-R window base (cycles 0, 64, 128)

  for (int t = tbeg; t < tend; ++t) {
    const int j0 = t * 64;
    const int tt = (t - tbeg) & 1;
    const bool hasn = (t + 1 < tend);
    __syncthreads();  // SINGLE barrier: all commits for tile t now visible

    uint4 kpf[2], rpf[2], vpf[2];
    if (hasn) {
      const int j0n = j0 + 64;
      const int W0n = 2048 + j0n - i0 - 63;
#pragma unroll
      for (int it = 0; it < 2; ++it) {
        int qk = tid + it * 256, row = qk >> 3, cl = qk & 7;
        kpf[it] = *(const uint4*)(khb + (size_t)(b * S_LEN + j0n + row) * DMODEL + n * 64 + cl * 8);
      }
      // only the 64 NEW rows of the next window: logical u' in [64,128)
#pragma unroll
      for (int it = 0; it < 2; ++it) {
        int qk = tid + it * 256, rnew = qk >> 3, cl = qk & 7;
        rpf[it] = *(const uint4*)(rhb + (size_t)(W0n + 64 + rnew) * DMODEL + n * 64 + cl * 8);
      }
#pragma unroll
      for (int it = 0; it < 2; ++it)
        vpf[it] = *(const uint4*)(vhb + (size_t)(b * S_LEN + j0n + srow + it * 32) * DMODEL + n * 64 + sg8);
    }
    unsigned wlo = segw[b * 64 + (j0 >> 5)];
    unsigned whi = segw[b * 64 + (j0 >> 5) + 1];

    // content MFMAs: cf[s][rr] = S[j = j0+s*16+g*4+rr][i = qrow]
    __builtin_amdgcn_s_setprio(1);
    f32x4 cf[4] = {};
#pragma unroll
    for (int s = 0; s < 4; ++s) {
      int row = s * 16 + r16;
      bf16x8 k0 = *(const bf16x8*)&Klds[tt][row][(g ^ (row & 7)) * 8];
      bf16x8 k1 = *(const bf16x8*)&Klds[tt][row][((4 + g) ^ (row & 7)) * 8];
      cf[s] = __builtin_amdgcn_mfma_f32_16x16x32_bf16(k0, qw[0], cf[s], 0, 0, 0);
      cf[s] = __builtin_amdgcn_mfma_f32_16x16x32_bf16(k1, qw[1], cf[s], 0, 0, 0);
    }
    // pos MFMAs -> PosL; circular phys row = (A0m + logical) mod 192
#pragma unroll
    for (int sp = 0; sp < 5; ++sp) {
      int lrow = 48 - w * 16 + sp * 16 + r16;
      int prow = lrow + A0m; if (prow >= 192) prow -= 192;
      bf16x8 r0 = *(const bf16x8*)&Rlds[prow][(g ^ (prow & 7)) * 8];
      bf16x8 r1 = *(const bf16x8*)&Rlds[prow][((4 + g) ^ (prow & 7)) * 8];
      f32x4 pf = {};
      pf = __builtin_amdgcn_mfma_f32_16x16x32_bf16(r0, qr[0], pf, 0, 0, 0);
      pf = __builtin_amdgcn_mfma_f32_16x16x32_bf16(r1, qr[1], pf, 0, 0, 0);
      uint2 pw;
      pw.x = cvtpk(pf[0], pf[1]);
      pw.y = cvtpk(pf[2], pf[3]);
      *(uint2*)&SPw[r16 * 84 + sp * 16 + g * 4] = pw;
    }
    __builtin_amdgcn_s_setprio(0);
    // softmax (lane-local row = qrow). Read pos first (wave-lockstep => no race
    // with the Ps writes below into the same SP buffer).
    ushort_t pu[4][4];
#pragma unroll
    for (int s = 0; s < 4; ++s)
#pragma unroll
      for (int rr = 0; rr < 4; ++rr)
        pu[s][rr] = (ushort_t)SPw[r16 * 84 + (15 - r16) + s * 16 + g * 4 + rr];
    float vals[4][4];
    float vmax = -1e30f;
    const bool diag = (t == x);
#pragma unroll
    for (int s = 0; s < 4; ++s) {
      unsigned word = (s < 2) ? wlo : whi;
#pragma unroll
      for (int rr = 0; rr < 4; ++rr) {
        int p = s * 16 + g * 4 + rr;
        int bitv = (word >> (p & 31)) & 1;
        float sv = cf[s][rr] + b2f(pu[s][rr]) + ((bitv == ai) ? sb1 : sb0);
        if (diag && (p > w * 16 + r16)) sv -= 1e6f;
        vals[s][rr] = sv;
        vmax = fmaxf(vmax, sv);
      }
    }
    vmax = fmaxf(vmax, __shfl_xor(vmax, 16));
    vmax = fmaxf(vmax, __shfl_xor(vmax, 32));
    float scl = 1.f;
    bool resc = !__all(vmax <= m_r + 8.f);
    if (resc) {
      float mnew = fmaxf(m_r, vmax);
      scl = __expf(m_r - mnew);
      m_r = mnew;
    }
    float pex[4][4];
    float psum = 0.f;
#pragma unroll
    for (int s = 0; s < 4; ++s)
#pragma unroll
      for (int rr = 0; rr < 4; ++rr) {
        pex[s][rr] = __expf(vals[s][rr] - m_r);
        psum += pex[s][rr];
      }
    l_r = l_r * scl + psum;
#pragma unroll
    for (int s = 0; s < 4; ++s) {
      uint2 pw;
      pw.x = cvtpk(pex[s][0], pex[s][1]);
      pw.y = cvtpk(pex[s][2], pex[s][3]);
      *(uint2*)&SPw[r16 * 72 + s * 16 + g * 4] = pw;
    }

    // commits for tile t+1 -- all target regions last read by tile t-1:
    // K -> other buffer; R -> third half (A0m+128..A0m+192 mod 192); V -> other.
    // Visible to other waves at the next loop-top barrier.
    if (hasn) {
#pragma unroll
      for (int it = 0; it < 2; ++it) {
        int qk = tid + it * 256, row = qk >> 3, cl = qk & 7;
        *(uint4*)&Klds[tt ^ 1][row][(cl ^ (row & 7)) * 8] = kpf[it];
      }
#pragma unroll
      for (int it = 0; it < 2; ++it) {
        int qk = tid + it * 256, rnew = qk >> 3, cl = qk & 7;
        int pc = rnew + A0m + 128; if (pc >= 192) pc -= 192;
        *(uint4*)&Rlds[pc][(cl ^ (pc & 7)) * 8] = rpf[it];
      }
      const int dst = tt ^ 1;
#pragma unroll
      for (int it = 0; it < 2; ++it) {
        int jj = srow + it * 32;
        union { uint4 v; ushort_t us[8]; } vv; vv.v = vpf[it];
#pragma unroll
        for (int e = 0; e < 8; ++e) {
          int hh = sg8 + e;
          VsT[dst][hh][((jj >> 3) ^ (hh >> 3)) * 8 + (jj & 7)] = (short)vv.us[e];
        }
      }
    }
    // PV: o[s][rr] at (i-row = g*4+rr, h = s*16+r16)
    if (resc) {
      float sclb[4];
#pragma unroll
      for (int rr = 0; rr < 4; ++rr) sclb[rr] = __shfl(scl, g * 4 + rr);
#pragma unroll
      for (int s = 0; s < 4; ++s)
#pragma unroll
        for (int rr = 0; rr < 4; ++rr) o[s][rr] *= sclb[rr];
    }
    bf16x8 pa0 = *(const bf16x8*)&SPw[r16 * 72 + g * 8];
    bf16x8 pa1 = *(const bf16x8*)&SPw[r16 * 72 + 32 + g * 8];
    __builtin_amdgcn_s_setprio(1);
#pragma unroll
    for (int s = 0; s < 4; ++s) {
      int hh = s * 16 + r16;
      bf16x8 v0 = *(const bf16x8*)&VsT[tt][hh][(g ^ (hh >> 3)) * 8];
      bf16x8 v1 = *(const bf16x8*)&VsT[tt][hh][((4 + g) ^ (hh >> 3)) * 8];
      o[s] = __builtin_amdgcn_mfma_f32_16x16x32_bf16(pa0, v0, o[s], 0, 0, 0);
      o[s] = __builtin_amdgcn_mfma_f32_16x16x32_bf16(pa1, v1, o[s], 0, 0, 0);
    }
    __builtin_amdgcn_s_setprio(0);
    A0m += 64; if (A0m >= 192) A0m -= 192;
  }

  // epilogue: m/l; o bounced through wave-private SPw into packed uint4 stores
  float l_row = l_r;
  l_row += __shfl_xor(l_row, 16);
  l_row += __shfl_xor(l_row, 32);
  if (lane < 16) {
    ml[hx * 2 * BNS + rowbase + w * 16 + r16] = m_r;
    ml[(hx * 2 + 1) * BNS + rowbase + w * 16 + r16] = l_row;
  }
#pragma unroll
  for (int s = 0; s < 4; ++s) {
    uint2 pw;
    pw.x = cvtpk(o[s][0], o[s][1]);
    pw.y = cvtpk(o[s][2], o[s][3]);
    // store 4 bf16 (rows g*4..g*4+3, col s*16+r16) into the wave-private bounce
    SPw[(g * 4 + 0) * 64 + s * 16 + r16] = (short)(pw.x & 0xFFFF);
    SPw[(g * 4 + 1) * 64 + s * 16 + r16] = (short)(pw.x >> 16);
    SPw[(g * 4 + 2) * 64 + s * 16 + r16] = (short)(pw.y & 0xFFFF);
    SPw[(g * 4 + 3) * 64 + s * 16 + r16] = (short)(pw.y >> 16);
  }
  {
    const int lr2 = lane >> 2;            // 0..15: local row
    const int cseg = (lane & 3) * 16;     // 0,16,32,48
    uint4 pa = *(const uint4*)&SPw[lr2 * 64 + cseg];
    uint4 pb = *(const uint4*)&SPw[lr2 * 64 + cseg + 8];
    size_t base = (size_t)(hx * BNS + rowbase + w * 16 + lr2) * 64 + cseg;
    *(uint4*)(opart + base) = pa;
    *(uint4*)(opart + base + 8) = pb;
  }
}

// ---------------------------------------------------------------------------
// Merge the two j-halves: o = (o0*e^{m0-m} + o1*e^{m1-m}) / l
// ---------------------------------------------------------------------------
__global__ __launch_bounds__(256) void merge_kernel(
    const ushort_t* __restrict__ opart, const float* __restrict__ ml,
    ushort_t* __restrict__ av) {
  const int BNS = 65536;
  int row = blockIdx.x * 4 + (threadIdx.x >> 6);
  int lane = threadIdx.x & 63;
  float m0 = ml[row], l0 = ml[BNS + row];
  float m1 = ml[2 * BNS + row], l1 = ml[3 * BNS + row];
  float m = fmaxf(m0, m1);
  float a0 = __expf(m0 - m), a1 = __expf(m1 - m);
  float inv = 1.f / (l0 * a0 + l1 * a1);
  float o0 = b2f(opart[(size_t)row * 64 + lane]);
  float o1 = b2f(opart[(size_t)(BNS + row) * 64 + lane]);
  float ov = (o0 * a0 + o1 * a1) * inv;
  int bI = row >> 15, nI = (row >> 11) & 15, iI = row & 2047;
  av[(size_t)(bI * 2048 + iI) * 1024 + nI * 64 + lane] = (ushort_t)f2b(ov);
}

// ---------------------------------------------------------------------------
// Residual + LayerNorm
// ---------------------------------------------------------------------------
__global__ __launch_bounds__(256) void ln_kernel(
    const float* __restrict__ q, const float* __restrict__ ao,
    const float* __restrict__ ln_g, const float* __restrict__ ln_b,
    float* __restrict__ out) {
  int row = blockIdx.x;
  const float* xq = q + (size_t)row * 1024;
  const float* xa = ao + (size_t)row * 1024;
  float x[4], lsum = 0.f, lsq = 0.f;
#pragma unroll
  for (int e = 0; e < 4; ++e) {
    int d = threadIdx.x + e * 256;
    x[e] = xq[d] + xa[d];
    lsum += x[e]; lsq += x[e] * x[e];
  }
  for (int off = 1; off < 64; off <<= 1) {
    lsum += __shfl_xor(lsum, off);
    lsq += __shfl_xor(lsq, off);
  }
  __shared__ float red[8];
  int wv = threadIdx.x >> 6, ln = threadIdx.x & 63;
  if (ln == 0) { red[wv] = lsum; red[4 + wv] = lsq; }
  __syncthreads();
  lsum = red[0] + red[1] + red[2] + red[3];
  lsq = red[4] + red[5] + red[6] + red[7];
  float mu = lsum * (1.f / 1024.f);
  float var = lsq * (1.f / 1024.f) - mu * mu;
  float inv = rsqrtf(var + 1e-5f);
#pragma unroll
  for (int e = 0; e < 4; ++e) {
    int d = threadIdx.x + e * 256;
    out[(size_t)row * 1024 + d] = (x[e] - mu) * inv * ln_g[d] + ln_b[d];
  }
}

// ---------------------------------------------------------------------------
extern "C" void kernel_launch(void* const* d_in, const int* in_sizes, int n_in,
                              void* d_out, int out_size, void* d_ws, size_t ws_size,
                              hipStream_t stream) {
  const float* q   = (const float*)d_in[0];
  const float* k   = (const float*)d_in[1];
  const float* v   = (const float*)d_in[2];
  const float* pe  = (const float*)d_in[3];
  const void*  seg = d_in[4];
  const float* qW  = (const float*)d_in[6];
  const float* kW  = (const float*)d_in[7];
  const float* kb  = (const float*)d_in[8];
  const float* vW  = (const float*)d_in[9];
  const float* vb  = (const float*)d_in[10];
  const float* rwb = (const float*)d_in[11];
  const float* rrb = (const float*)d_in[12];
  const float* rK  = (const float*)d_in[13];
  const float* rsb = (const float*)d_in[14];
  const float* sem = (const float*)d_in[15];
  const float* pW  = (const float*)d_in[16];
  const float* pb  = (const float*)d_in[17];
  const float* lng = (const float*)d_in[18];
  const float* lnb = (const float*)d_in[19];
  float* out = (float*)d_out;

  const size_t MB = 1u << 20;
  char* W = (char*)d_ws;
  ushort_t* qwb  = (ushort_t*)(W + 0 * MB);     // 8 MB
  ushort_t* qrb  = (ushort_t*)(W + 8 * MB);     // 8 MB
  ushort_t* opart = (ushort_t*)(W + 16 * MB);   // 16 MB
  ushort_t* wtq  = (ushort_t*)(W + 32 * MB);
  ushort_t* wtk  = (ushort_t*)(W + 34 * MB);
  ushort_t* wtv  = (ushort_t*)(W + 36 * MB);
  ushort_t* wtr  = (ushort_t*)(W + 38 * MB);
  ushort_t* wtp  = (ushort_t*)(W + 40 * MB);
  ushort_t* av   = (ushort_t*)(W + 42 * MB);    // 8 MB
  ushort_t* kh   = (ushort_t*)(W + 50 * MB);
  ushort_t* vh   = (ushort_t*)(W + 58 * MB);
  ushort_t* rh   = (ushort_t*)(W + 66 * MB);
  unsigned* segw = (unsigned*)(W + 74 * MB);
  float2*   sbp  = (float2*)(W + 74 * MB + 65536);
  float*    ml   = (float*)(W + 75 * MB);
  float*    ao   = (float*)(W + 50 * MB);       // 16MB over kh+vh (dead post-attn)

  seg_extract_kernel<<<dim3(16), dim3(256), 0, stream>>>((const unsigned int*)seg, segw);
  convT_kernel<<<dim3(16, 16, 5), dim3(256), 0, stream>>>(qW, kW, vW, rK, pW,
                                                          wtq, wtk, wtv, wtr, wtp);
  // batched projection GEMMs over fp32 inputs; z==0 fuses qprep
  gemm4_kernel<<<dim3(32, 8, 4), dim3(256), 0, stream>>>(
      q, k, v, pe, wtq, wtk, wtv, wtr, kb, vb, rwb, rrb, rsb, sem,
      qwb, qrb, sbp, kh, vh, rh);

  attn_kernel<<<dim3(2048), dim3(256), 0, stream>>>(qwb, qrb, kh, vh, rh,
                                                    sbp, segw, opart, ml);
  merge_kernel<<<dim3(16384), dim3(256), 0, stream>>>(opart, ml, av);

  gemm_post_kernel<<<dim3(64, 8), dim3(256), 0, stream>>>(av, wtp, pb, ao);
  ln_kernel<<<dim3(4096), dim3(256), 0, stream>>>(q, ao, lng, lnb, out);
}

// Round 20
// 228.887 us; speedup vs baseline: 1.0074x; 1.0074x over previous
//
#include <hip/hip_runtime.h>
#include <hip/hip_bf16.h>

typedef __attribute__((ext_vector_type(8))) short bf16x8;
typedef __attribute__((ext_vector_type(4))) float f32x4;
typedef unsigned short ushort_t;

#define S_LEN 2048
#define DMODEL 1024
#define NORM_F 0.125f

__device__ __forceinline__ short f2b(float x) {
  union { float f; unsigned u; } c; c.f = x;
  unsigned r = (c.u + 0x7FFFu + ((c.u >> 16) & 1u)) >> 16;
  return (short)r;
}
__device__ __forceinline__ float b2f(ushort_t u) {
  union { unsigned u; float f; } c; c.u = ((unsigned)u) << 16; return c.f;
}
__device__ __forceinline__ unsigned cvtpk(float lo, float hi) {
  unsigned r;
  asm volatile("v_cvt_pk_bf16_f32 %0, %1, %2" : "=v"(r) : "v"(lo), "v"(hi));
  return r;
}
__device__ __forceinline__ uint4 pack8(float4 a, float4 b) {
  union { ushort_t us[8]; uint4 v; } o;
  o.us[0] = (ushort_t)f2b(a.x); o.us[1] = (ushort_t)f2b(a.y);
  o.us[2] = (ushort_t)f2b(a.z); o.us[3] = (ushort_t)f2b(a.w);
  o.us[4] = (ushort_t)f2b(b.x); o.us[5] = (ushort_t)f2b(b.y);
  o.us[6] = (ushort_t)f2b(b.z); o.us[7] = (ushort_t)f2b(b.w);
  return o.v;
}

// ---------------------------------------------------------------------------
// Segment bits, packed: segw[b*64 + (i>>5)] bit (i&31) = seg id of (b, i).
// ---------------------------------------------------------------------------
__global__ void seg_extract_kernel(const unsigned int* __restrict__ seg_raw,
                                   unsigned* __restrict__ segw) {
  __shared__ int bad_int, bad_flt;
  int tid = threadIdx.x;
  if (tid == 0) { bad_int = 0; bad_flt = 0; }
  __syncthreads();
  for (int i = tid; i < 2048; i += 256) {
    unsigned v = seg_raw[i];
    if (v > 1u) atomicOr(&bad_int, 1);
    if (v != 0u && v != 0x3F800000u) atomicOr(&bad_flt, 1);
  }
  __syncthreads();
  int mode = bad_int ? (bad_flt ? 2 : 1) : 0;
  const unsigned char* u8 = (const unsigned char*)seg_raw;
  int P = blockIdx.x * 256 + tid;       // [0, 4096)
  int b = P >> 11, i = P & 2047;
  size_t off = (size_t)b * S_LEN * S_LEN + i;
  int bit;
  if (mode == 0)      bit = (int)(seg_raw[off] & 1u);
  else if (mode == 1) bit = (seg_raw[off] != 0u) ? 1 : 0;
  else                bit = (int)(u8[off] & 1u);
  unsigned long long mk = __ballot(bit);
  if ((tid & 63) == 0) {
    segw[P >> 5] = (unsigned)mk;
    segw[(P >> 5) + 1] = (unsigned)(mk >> 32);
  }
}

// ---------------------------------------------------------------------------
// Weight transpose+convert: W fp32 [1024 k][1024 n] -> Wt bf16 [n][k]
// ---------------------------------------------------------------------------
__global__ __launch_bounds__(256) void convT_kernel(
    const float* __restrict__ s0, const float* __restrict__ s1,
    const float* __restrict__ s2, const float* __restrict__ s3,
    const float* __restrict__ s4,
    ushort_t* __restrict__ d0, ushort_t* __restrict__ d1,
    ushort_t* __restrict__ d2, ushort_t* __restrict__ d3,
    ushort_t* __restrict__ d4) {
  int z = blockIdx.z;
  const float* src = z == 0 ? s0 : z == 1 ? s1 : z == 2 ? s2 : z == 3 ? s3 : s4;
  ushort_t* dst = z == 0 ? d0 : z == 1 ? d1 : z == 2 ? d2 : z == 3 ? d3 : d4;
  __shared__ float Tl[64][68];
  int tid = threadIdx.x;
  int k0 = blockIdx.x * 64, n0 = blockIdx.y * 64;
#pragma unroll
  for (int it = 0; it < 4; ++it) {
    int idx = tid + it * 256;
    int r = idx >> 4, c4 = (idx & 15) * 4;
    *(float4*)&Tl[r][c4] = *(const float4*)(src + (size_t)(k0 + r) * 1024 + n0 + c4);
  }
  __syncthreads();
#pragma unroll
  for (int it = 0; it < 2; ++it) {
    int idx = tid + it * 256;
    int nn = idx >> 3, kc = idx & 7;
    union { ushort_t us[8]; uint4 v; } o;
#pragma unroll
    for (int e = 0; e < 8; ++e) o.us[e] = (ushort_t)f2b(Tl[kc * 8 + e][nn]);
    *(uint4*)(dst + (size_t)(n0 + nn) * 1024 + k0 + kc * 8) = o.v;
  }
}

// ---------------------------------------------------------------------------
// Batched projection GEMM over fp32 activations (in-register bf16 convert):
// blockIdx.z selects {q,k,v,pe}. z==0 epilogue fuses qprep.
// ---------------------------------------------------------------------------
__global__ __launch_bounds__(256) void gemm4_kernel(
    const float* __restrict__ a0, const float* __restrict__ a1,
    const float* __restrict__ a2, const float* __restrict__ a3,
    const ushort_t* __restrict__ w0, const ushort_t* __restrict__ w1,
    const ushort_t* __restrict__ w2, const ushort_t* __restrict__ w3,
    const float* __restrict__ kb, const float* __restrict__ vb,
    const float* __restrict__ rwb, const float* __restrict__ rrb,
    const float* __restrict__ rsb, const float* __restrict__ sem,
    ushort_t* __restrict__ qwb, ushort_t* __restrict__ qrb,
    float2* __restrict__ sbp,
    ushort_t* __restrict__ c1, ushort_t* __restrict__ c2,
    ushort_t* __restrict__ c3) {
  const int z = blockIdx.z;
  const float* A     = z == 0 ? a0 : z == 1 ? a1 : z == 2 ? a2 : a3;
  const ushort_t* Wt = z == 0 ? w0 : z == 1 ? w1 : z == 2 ? w2 : w3;

  __shared__ short A_lds[128][40];
  __shared__ short B_lds[128][40];
  const int tid = threadIdx.x;
  const int wave = tid >> 6, lane = tid & 63;
  const int r16 = lane & 15, g = lane >> 4;
  const int wm = wave >> 1, wn = wave & 1;
  const int m0 = blockIdx.x * 128, n0 = blockIdx.y * 128;
  const int sr = tid >> 2, sseg = (tid & 3) * 8;
  f32x4 acc[4][4] = {};
  float4 fa0a = *(const float4*)(A + (size_t)(m0 + sr) * 1024 + sseg);
  float4 fa0b = *(const float4*)(A + (size_t)(m0 + sr) * 1024 + sseg + 4);
  float4 fa1a = *(const float4*)(A + (size_t)(m0 + 64 + sr) * 1024 + sseg);
  float4 fa1b = *(const float4*)(A + (size_t)(m0 + 64 + sr) * 1024 + sseg + 4);
  uint4 rb0 = *(const uint4*)(Wt + (size_t)(n0 + sr) * 1024 + sseg);
  uint4 rb1 = *(const uint4*)(Wt + (size_t)(n0 + 64 + sr) * 1024 + sseg);
  for (int k0 = 0; k0 < 1024; k0 += 32) {
    *(uint4*)&A_lds[sr][sseg] = pack8(fa0a, fa0b);
    *(uint4*)&A_lds[64 + sr][sseg] = pack8(fa1a, fa1b);
    *(uint4*)&B_lds[sr][sseg] = rb0;
    *(uint4*)&B_lds[64 + sr][sseg] = rb1;
    __syncthreads();
    if (k0 + 32 < 1024) {
      fa0a = *(const float4*)(A + (size_t)(m0 + sr) * 1024 + k0 + 32 + sseg);
      fa0b = *(const float4*)(A + (size_t)(m0 + sr) * 1024 + k0 + 32 + sseg + 4);
      fa1a = *(const float4*)(A + (size_t)(m0 + 64 + sr) * 1024 + k0 + 32 + sseg);
      fa1b = *(const float4*)(A + (size_t)(m0 + 64 + sr) * 1024 + k0 + 32 + sseg + 4);
      rb0 = *(const uint4*)(Wt + (size_t)(n0 + sr) * 1024 + k0 + 32 + sseg);
      rb1 = *(const uint4*)(Wt + (size_t)(n0 + 64 + sr) * 1024 + k0 + 32 + sseg);
    }
    bf16x8 af[4], bfr[4];
#pragma unroll
    for (int fm = 0; fm < 4; ++fm)
      af[fm] = *(const bf16x8*)&A_lds[wm * 64 + fm * 16 + r16][g * 8];
#pragma unroll
    for (int fn = 0; fn < 4; ++fn)
      bfr[fn] = *(const bf16x8*)&B_lds[wn * 64 + fn * 16 + r16][g * 8];
#pragma unroll
    for (int fm = 0; fm < 4; ++fm)
#pragma unroll
      for (int fn = 0; fn < 4; ++fn)
        acc[fm][fn] = __builtin_amdgcn_mfma_f32_16x16x32_bf16(af[fm], bfr[fn], acc[fm][fn], 0, 0, 0);
    __syncthreads();
  }

  if (z == 0) {
    // fused qprep epilogue: this wave's 64-col half is one full head.
    float rwbN[4], rrbN[4], rsbN[4], s0c[4], s1c[4];
#pragma unroll
    for (int fn = 0; fn < 4; ++fn) {
      int col = n0 + wn * 64 + fn * 16 + r16;
      rwbN[fn] = rwb[col] * NORM_F;
      rrbN[fn] = rrb[col] * NORM_F;
      rsbN[fn] = rsb[col] * NORM_F;
      s0c[fn] = sem[col];
      s1c[fn] = sem[1024 + col];
    }
    const int nI = (n0 >> 6) + wn;   // head index 0..15
#pragma unroll
    for (int fm = 0; fm < 4; ++fm)
#pragma unroll
      for (int rr = 0; rr < 4; ++rr) {
        int row = m0 + wm * 64 + fm * 16 + g * 4 + rr;
        float p0 = 0.f, p1 = 0.f;
#pragma unroll
        for (int fn = 0; fn < 4; ++fn) {
          float vv = acc[fm][fn][rr] * NORM_F;
          size_t off = (size_t)row * 1024 + n0 + wn * 64 + fn * 16 + r16;
          qwb[off] = (ushort_t)f2b(vv + rwbN[fn]);
          qrb[off] = (ushort_t)f2b(vv + rrbN[fn]);
          float qs = vv + rsbN[fn];
          p0 += qs * s0c[fn];
          p1 += qs * s1c[fn];
        }
        p0 += __shfl_xor(p0, 1); p0 += __shfl_xor(p0, 2);
        p0 += __shfl_xor(p0, 4); p0 += __shfl_xor(p0, 8);
        p1 += __shfl_xor(p1, 1); p1 += __shfl_xor(p1, 2);
        p1 += __shfl_xor(p1, 4); p1 += __shfl_xor(p1, 8);
        if (r16 == 0) {
          int bI = row >> 11, iI = row & 2047;
          sbp[((size_t)bI * 16 + nI) * 2048 + iI] = make_float2(p0, p1);
        }
      }
  } else {
    const float* bias = z == 1 ? kb : z == 2 ? vb : (const float*)nullptr;
    ushort_t* C = z == 1 ? c1 : z == 2 ? c2 : c3;
    float bv[4];
#pragma unroll
    for (int fn = 0; fn < 4; ++fn)
      bv[fn] = bias ? bias[n0 + wn * 64 + fn * 16 + r16] : 0.f;
#pragma unroll
    for (int fm = 0; fm < 4; ++fm)
#pragma unroll
      for (int fn = 0; fn < 4; ++fn)
#pragma unroll
        for (int rr = 0; rr < 4; ++rr) {
          float vv = acc[fm][fn][rr] + bv[fn];
          size_t off = (size_t)(m0 + wm * 64 + fm * 16 + g * 4 + rr) * 1024 +
                       n0 + wn * 64 + fn * 16 + r16;
          C[off] = (ushort_t)f2b(vv);
        }
  }
}

// ---------------------------------------------------------------------------
// Post-projection GEMM, 64x128 tile (512 blocks = 2/CU), fp32 out.
// ---------------------------------------------------------------------------
__global__ __launch_bounds__(256) void gemm_post_kernel(
    const ushort_t* __restrict__ A, const ushort_t* __restrict__ Wt,
    const float* __restrict__ bias, float* __restrict__ C) {
  __shared__ short A_lds[64][40];
  __shared__ short B_lds[128][40];
  const int tid = threadIdx.x;
  const int wave = tid >> 6, lane = tid & 63;
  const int r16 = lane & 15, g = lane >> 4;
  const int wm = wave >> 1, wn = wave & 1;
  const int m0 = blockIdx.x * 64, n0 = blockIdx.y * 128;
  const int sr = tid >> 2, sseg = (tid & 3) * 8;
  f32x4 acc[2][4] = {};
  uint4 ra0 = *(const uint4*)(A + (size_t)(m0 + sr) * 1024 + sseg);
  uint4 rb0 = *(const uint4*)(Wt + (size_t)(n0 + sr) * 1024 + sseg);
  uint4 rb1 = *(const uint4*)(Wt + (size_t)(n0 + 64 + sr) * 1024 + sseg);
  for (int k0 = 0; k0 < 1024; k0 += 32) {
    *(uint4*)&A_lds[sr][sseg] = ra0;
    *(uint4*)&B_lds[sr][sseg] = rb0;
    *(uint4*)&B_lds[64 + sr][sseg] = rb1;
    __syncthreads();
    if (k0 + 32 < 1024) {
      ra0 = *(const uint4*)(A + (size_t)(m0 + sr) * 1024 + k0 + 32 + sseg);
      rb0 = *(const uint4*)(Wt + (size_t)(n0 + sr) * 1024 + k0 + 32 + sseg);
      rb1 = *(const uint4*)(Wt + (size_t)(n0 + 64 + sr) * 1024 + k0 + 32 + sseg);
    }
    bf16x8 af[2], bfr[4];
#pragma unroll
    for (int fm = 0; fm < 2; ++fm)
      af[fm] = *(const bf16x8*)&A_lds[wm * 32 + fm * 16 + r16][g * 8];
#pragma unroll
    for (int fn = 0; fn < 4; ++fn)
      bfr[fn] = *(const bf16x8*)&B_lds[wn * 64 + fn * 16 + r16][g * 8];
#pragma unroll
    for (int fm = 0; fm < 2; ++fm)
#pragma unroll
      for (int fn = 0; fn < 4; ++fn)
        acc[fm][fn] = __builtin_amdgcn_mfma_f32_16x16x32_bf16(af[fm], bfr[fn], acc[fm][fn], 0, 0, 0);
    __syncthreads();
  }
  float bv[4];
#pragma unroll
  for (int fn = 0; fn < 4; ++fn)
    bv[fn] = bias ? bias[n0 + wn * 64 + fn * 16 + r16] : 0.f;
#pragma unroll
  for (int fm = 0; fm < 2; ++fm)
#pragma unroll
    for (int fn = 0; fn < 4; ++fn)
#pragma unroll
      for (int rr = 0; rr < 4; ++rr) {
        size_t off = (size_t)(m0 + wm * 32 + fm * 16 + g * 4 + rr) * 1024 +
                     n0 + wn * 64 + fn * 16 + r16;
        C[off] = acc[fm][fn][rr] + bv[fn];
      }
}

// ---------------------------------------------------------------------------
// Fused causal relative attention (R13 structure: circular R, V scatter with
// 3-bit XOR, setprio, XCD swizzle) + packed coalesced epilogue via SPw bounce.
// ---------------------------------------------------------------------------
__global__ __launch_bounds__(256) void attn_kernel(
    const ushort_t* __restrict__ qwb, const ushort_t* __restrict__ qrb,
    const ushort_t* __restrict__ khb, const ushort_t* __restrict__ vhb,
    const ushort_t* __restrict__ rhb, const float2* __restrict__ sbp,
    const unsigned* __restrict__ segw, ushort_t* __restrict__ opart,
    float* __restrict__ ml) {
  __shared__ short Klds[64][64];
  __shared__ short Rlds[128][64];
  __shared__ short VsT[2][64][72];
  __shared__ short SP[4][1344];

  const int tid = threadIdx.x;
  const int w = tid >> 6, lane = tid & 63;
  const int r16 = lane & 15, g = lane >> 4;
  // XCD swizzle: lin -> (group g in [0,32), j in [0,64)); XCD = lin % 8 = g % 8
  const int lin = (int)blockIdx.x;
  const int grp = (lin & 7) + ((lin >> 9) << 3);
  const int j = (lin >> 3) & 63;
  const int x = 31 - (j >> 1);
  const int hx = j & 1;
  const int i0 = x * 64;
  const int nh = (x + 2) >> 1;
  const int tbeg = hx ? nh : 0;
  const int tend = hx ? (x + 1) : nh;
  const int n = grp & 15, b = grp >> 4;
  const int BNS = 65536;
  const int rowbase = (b * 16 + n) * 2048 + i0;

  if (tbeg >= tend) {  // empty half (only hx==1, x==0)
    const int il0 = w * 16 + g * 4;
#pragma unroll
    for (int rr = 0; rr < 4; ++rr) {
#pragma unroll
      for (int s = 0; s < 4; ++s)
        opart[(size_t)(BNS + rowbase + il0 + rr) * 64 + s * 16 + r16] = 0;
      if (r16 == 0) {
        ml[2 * BNS + rowbase + il0 + rr] = -1e30f;
        ml[3 * BNS + rowbase + il0 + rr] = 0.f;
      }
    }
    return;
  }

  short* SPw = &SP[w][0];
  const int srow = tid >> 3, sg8 = (tid & 7) * 8;

  // per-lane persistent state (q-row = r16 within this wave's 16 rows)
  const int qrow = i0 + w * 16 + r16;
  const ushort_t* qwp = qwb + (size_t)(b * S_LEN + qrow) * DMODEL + n * 64 + g * 8;
  const ushort_t* qrp = qrb + (size_t)(b * S_LEN + qrow) * DMODEL + n * 64 + g * 8;
  bf16x8 qw[2], qr[2];
  qw[0] = *(const bf16x8*)qwp;  qw[1] = *(const bf16x8*)(qwp + 32);
  qr[0] = *(const bf16x8*)qrp;  qr[1] = *(const bf16x8*)(qrp + 32);
  float2 sbv = sbp[((size_t)b * 16 + n) * 2048 + qrow];
  const float sb0 = sbv.x, sb1 = sbv.y;
  const int ai = (segw[b * 64 + (qrow >> 5)] >> (qrow & 31)) & 1;
  const int iw0 = i0 + w * 16;

  // prologue: stage tile tbeg (K, R swizzled; V scattered, 3-bit chunk XOR)
  // R: full 128-row window at phys == logical (xm = 0 at tbeg).
  {
    const int j0 = tbeg * 64;
    const int W0 = 2048 + j0 - i0 - 63;
#pragma unroll
    for (int it = 0; it < 2; ++it) {
      int qk = tid + it * 256, row = qk >> 3, cl = qk & 7;
      uint4 kv = *(const uint4*)(khb + (size_t)(b * S_LEN + j0 + row) * DMODEL + n * 64 + cl * 8);
      *(uint4*)&Klds[row][(cl ^ (row & 7)) * 8] = kv;
    }
#pragma unroll
    for (int it = 0; it < 4; ++it) {
      int qk = tid + it * 256, row = qk >> 3, cl = qk & 7;
      uint4 rv = *(const uint4*)(rhb + (size_t)(W0 + row) * DMODEL + n * 64 + cl * 8);
      *(uint4*)&Rlds[row][(cl ^ (row & 7)) * 8] = rv;
    }
#pragma unroll
    for (int it = 0; it < 2; ++it) {
      int jj = srow + it * 32;
      union { uint4 v; ushort_t us[8]; } vv;
      vv.v = *(const uint4*)(vhb + (size_t)(b * S_LEN + j0 + jj) * DMODEL + n * 64 + sg8);
#pragma unroll
      for (int e = 0; e < 8; ++e) {
        int hh = sg8 + e;
        VsT[0][hh][((jj >> 3) ^ (hh >> 3)) * 8 + (jj & 7)] = (short)vv.us[e];
      }
    }
  }

  float m_r = -1e30f, l_r = 0.f;
  f32x4 o[4] = {};

  for (int t = tbeg; t < tend; ++t) {
    const int j0 = t * 64;
    const int tt = (t - tbeg) & 1;
    const int xm = tt << 6;              // circular-R phase: phys = logical ^ xm
    const bool hasn = (t + 1 < tend);
    __syncthreads();  // barrier A: staged data for tile t visible

    uint4 kpf[2], rpf[2], vpf[2];
    if (hasn) {
      const int j0n = j0 + 64;
      const int W0n = 2048 + j0n - i0 - 63;
#pragma unroll
      for (int it = 0; it < 2; ++it) {
        int qk = tid + it * 256, row = qk >> 3, cl = qk & 7;
        kpf[it] = *(const uint4*)(khb + (size_t)(b * S_LEN + j0n + row) * DMODEL + n * 64 + cl * 8);
      }
      // only the 64 NEW rows of the next window: logical u' in [64,128)
#pragma unroll
      for (int it = 0; it < 2; ++it) {
        int qk = tid + it * 256, rnew = qk >> 3, cl = qk & 7;
        rpf[it] = *(const uint4*)(rhb + (size_t)(W0n + 64 + rnew) * DMODEL + n * 64 + cl * 8);
      }
#pragma unroll
      for (int it = 0; it < 2; ++it)
        vpf[it] = *(const uint4*)(vhb + (size_t)(b * S_LEN + j0n + srow + it * 32) * DMODEL + n * 64 + sg8);
    }
    unsigned wlo = segw[b * 64 + (j0 >> 5)];
    unsigned whi = segw[b * 64 + (j0 >> 5) + 1];

    // content MFMAs: cf[s][rr] = S[j = j0+s*16+g*4+rr][i = qrow]
    __builtin_amdgcn_s_setprio(1);
    f32x4 cf[4] = {};
#pragma unroll
    for (int s = 0; s < 4; ++s) {
      int row = s * 16 + r16;
      bf16x8 k0 = *(const bf16x8*)&Klds[row][(g ^ (row & 7)) * 8];
      bf16x8 k1 = *(const bf16x8*)&Klds[row][((4 + g) ^ (row & 7)) * 8];
      cf[s] = __builtin_amdgcn_mfma_f32_16x16x32_bf16(k0, qw[0], cf[s], 0, 0, 0);
      cf[s] = __builtin_amdgcn_mfma_f32_16x16x32_bf16(k1, qw[1], cf[s], 0, 0, 0);
    }
    // pos MFMAs -> PosL; circular phys row = logical ^ xm ((^64) keeps low 3 bits)
#pragma unroll
    for (int sp = 0; sp < 5; ++sp) {
      int lrow = 48 - w * 16 + sp * 16 + r16;
      int prow = lrow ^ xm;
      bf16x8 r0 = *(const bf16x8*)&Rlds[prow][(g ^ (prow & 7)) * 8];
      bf16x8 r1 = *(const bf16x8*)&Rlds[prow][((4 + g) ^ (prow & 7)) * 8];
      f32x4 pf = {};
      pf = __builtin_amdgcn_mfma_f32_16x16x32_bf16(r0, qr[0], pf, 0, 0, 0);
      pf = __builtin_amdgcn_mfma_f32_16x16x32_bf16(r1, qr[1], pf, 0, 0, 0);
      uint2 pw;
      pw.x = cvtpk(pf[0], pf[1]);
      pw.y = cvtpk(pf[2], pf[3]);
      *(uint2*)&SPw[r16 * 84 + sp * 16 + g * 4] = pw;
    }
    __builtin_amdgcn_s_setprio(0);
    // softmax (lane-local row = qrow). Read pos first (wave-lockstep => no race
    // with the Ps writes below into the same SP buffer).
    ushort_t pu[4][4];
#pragma unroll
    for (int s = 0; s < 4; ++s)
#pragma unroll
      for (int rr = 0; rr < 4; ++rr)
        pu[s][rr] = (ushort_t)SPw[r16 * 84 + (15 - r16) + s * 16 + g * 4 + rr];
    float vals[4][4];
    float vmax = -1e30f;
    const bool diag = (t == x);
#pragma unroll
    for (int s = 0; s < 4; ++s) {
      unsigned word = (s < 2) ? wlo : whi;
#pragma unroll
      for (int rr = 0; rr < 4; ++rr) {
        int p = s * 16 + g * 4 + rr;
        int bitv = (word >> (p & 31)) & 1;
        float sv = cf[s][rr] + b2f(pu[s][rr]) + ((bitv == ai) ? sb1 : sb0);
        if (diag && (p > w * 16 + r16)) sv -= 1e6f;
        vals[s][rr] = sv;
        vmax = fmaxf(vmax, sv);
      }
    }
    vmax = fmaxf(vmax, __shfl_xor(vmax, 16));
    vmax = fmaxf(vmax, __shfl_xor(vmax, 32));
    float scl = 1.f;
    bool resc = !__all(vmax <= m_r + 8.f);
    if (resc) {
      float mnew = fmaxf(m_r, vmax);
      scl = __expf(m_r - mnew);
      m_r = mnew;
    }
    float pex[4][4];
    float psum = 0.f;
#pragma unroll
    for (int s = 0; s < 4; ++s)
#pragma unroll
      for (int rr = 0; rr < 4; ++rr) {
        pex[s][rr] = __expf(vals[s][rr] - m_r);
        psum += pex[s][rr];
      }
    l_r = l_r * scl + psum;
#pragma unroll
    for (int s = 0; s < 4; ++s) {
      uint2 pw;
      pw.x = cvtpk(pex[s][0], pex[s][1]);
      pw.y = cvtpk(pex[s][2], pex[s][3]);
      *(uint2*)&SPw[r16 * 72 + s * 16 + g * 4] = pw;
    }
    __syncthreads();  // barrier B: K/R/V(t) LDS reads complete

    if (hasn) {
#pragma unroll
      for (int it = 0; it < 2; ++it) {
        int qk = tid + it * 256, row = qk >> 3, cl = qk & 7;
        *(uint4*)&Klds[row][(cl ^ (row & 7)) * 8] = kpf[it];
      }
      // commit new R rows at phys = rnew ^ xm (dead half of window t)
#pragma unroll
      for (int it = 0; it < 2; ++it) {
        int qk = tid + it * 256, rnew = qk >> 3, cl = qk & 7;
        int pr = rnew ^ xm;
        *(uint4*)&Rlds[pr][(cl ^ (pr & 7)) * 8] = rpf[it];
      }
      const int dst = tt ^ 1;
#pragma unroll
      for (int it = 0; it < 2; ++it) {
        int jj = srow + it * 32;
        union { uint4 v; ushort_t us[8]; } vv; vv.v = vpf[it];
#pragma unroll
        for (int e = 0; e < 8; ++e) {
          int hh = sg8 + e;
          VsT[dst][hh][((jj >> 3) ^ (hh >> 3)) * 8 + (jj & 7)] = (short)vv.us[e];
        }
      }
    }
    // PV: o[s][rr] at (i-row = g*4+rr, h = s*16+r16)
    if (resc) {
      float sclb[4];
#pragma unroll
      for (int rr = 0; rr < 4; ++rr) sclb[rr] = __shfl(scl, g * 4 + rr);
#pragma unroll
      for (int s = 0; s < 4; ++s)
#pragma unroll
        for (int rr = 0; rr < 4; ++rr) o[s][rr] *= sclb[rr];
    }
    bf16x8 pa0 = *(const bf16x8*)&SPw[r16 * 72 + g * 8];
    bf16x8 pa1 = *(const bf16x8*)&SPw[r16 * 72 + 32 + g * 8];
    __builtin_amdgcn_s_setprio(1);
#pragma unroll
    for (int s = 0; s < 4; ++s) {
      int hh = s * 16 + r16;
      bf16x8 v0 = *(const bf16x8*)&VsT[tt][hh][(g ^ (hh >> 3)) * 8];
      bf16x8 v1 = *(const bf16x8*)&VsT[tt][hh][((4 + g) ^ (hh >> 3)) * 8];
      o[s] = __builtin_amdgcn_mfma_f32_16x16x32_bf16(pa0, v0, o[s], 0, 0, 0);
      o[s] = __builtin_amdgcn_mfma_f32_16x16x32_bf16(pa1, v1, o[s], 0, 0, 0);
    }
    __builtin_amdgcn_s_setprio(0);
  }

  // epilogue: m/l as before; o bounced through wave-private SPw into packed
  // uint4 stores (wave writes 16 complete 128B lines, fully coalesced).
  float l_row = l_r;
  l_row += __shfl_xor(l_row, 16);
  l_row += __shfl_xor(l_row, 32);
  if (lane < 16) {
    ml[hx * 2 * BNS + rowbase + w * 16 + r16] = m_r;
    ml[(hx * 2 + 1) * BNS + rowbase + w * 16 + r16] = l_row;
  }
#pragma unroll
  for (int s = 0; s < 4; ++s) {
    uint2 pw;
    pw.x = cvtpk(o[s][0], o[s][1]);
    pw.y = cvtpk(o[s][2], o[s][3]);
    // store 4 bf16 (rows g*4..g*4+3, col s*16+r16) into the wave-private bounce
    SPw[(g * 4 + 0) * 64 + s * 16 + r16] = (short)(pw.x & 0xFFFF);
    SPw[(g * 4 + 1) * 64 + s * 16 + r16] = (short)(pw.x >> 16);
    SPw[(g * 4 + 2) * 64 + s * 16 + r16] = (short)(pw.y & 0xFFFF);
    SPw[(g * 4 + 3) * 64 + s * 16 + r16] = (short)(pw.y >> 16);
  }
  {
    const int lr2 = lane >> 2;            // 0..15: local row
    const int cseg = (lane & 3) * 16;     // 0,16,32,48
    uint4 pa = *(const uint4*)&SPw[lr2 * 64 + cseg];
    uint4 pb = *(const uint4*)&SPw[lr2 * 64 + cseg + 8];
    size_t base = (size_t)(hx * BNS + rowbase + w * 16 + lr2) * 64 + cseg;
    *(uint4*)(opart + base) = pa;
    *(uint4*)(opart + base + 8) = pb;
  }
}

// ---------------------------------------------------------------------------
// Merge the two j-halves: o = (o0*e^{m0-m} + o1*e^{m1-m}) / l
// ---------------------------------------------------------------------------
__global__ __launch_bounds__(256) void merge_kernel(
    const ushort_t* __restrict__ opart, const float* __restrict__ ml,
    ushort_t* __restrict__ av) {
  const int BNS = 65536;
  int row = blockIdx.x * 4 + (threadIdx.x >> 6);
  int lane = threadIdx.x & 63;
  float m0 = ml[row], l0 = ml[BNS + row];
  float m1 = ml[2 * BNS + row], l1 = ml[3 * BNS + row];
  float m = fmaxf(m0, m1);
  float a0 = __expf(m0 - m), a1 = __expf(m1 - m);
  float inv = 1.f / (l0 * a0 + l1 * a1);
  float o0 = b2f(opart[(size_t)row * 64 + lane]);
  float o1 = b2f(opart[(size_t)(BNS + row) * 64 + lane]);
  float ov = (o0 * a0 + o1 * a1) * inv;
  int bI = row >> 15, nI = (row >> 11) & 15, iI = row & 2047;
  av[(size_t)(bI * 2048 + iI) * 1024 + nI * 64 + lane] = (ushort_t)f2b(ov);
}

// ---------------------------------------------------------------------------
// Residual + LayerNorm
// ---------------------------------------------------------------------------
__global__ __launch_bounds__(256) void ln_kernel(
    const float* __restrict__ q, const float* __restrict__ ao,
    const float* __restrict__ ln_g, const float* __restrict__ ln_b,
    float* __restrict__ out) {
  int row = blockIdx.x;
  const float* xq = q + (size_t)row * 1024;
  const float* xa = ao + (size_t)row * 1024;
  float x[4], lsum = 0.f, lsq = 0.f;
#pragma unroll
  for (int e = 0; e < 4; ++e) {
    int d = threadIdx.x + e * 256;
    x[e] = xq[d] + xa[d];
    lsum += x[e]; lsq += x[e] * x[e];
  }
  for (int off = 1; off < 64; off <<= 1) {
    lsum += __shfl_xor(lsum, off);
    lsq += __shfl_xor(lsq, off);
  }
  __shared__ float red[8];
  int wv = threadIdx.x >> 6, ln = threadIdx.x & 63;
  if (ln == 0) { red[wv] = lsum; red[4 + wv] = lsq; }
  __syncthreads();
  lsum = red[0] + red[1] + red[2] + red[3];
  lsq = red[4] + red[5] + red[6] + red[7];
  float mu = lsum * (1.f / 1024.f);
  float var = lsq * (1.f / 1024.f) - mu * mu;
  float inv = rsqrtf(var + 1e-5f);
#pragma unroll
  for (int e = 0; e < 4; ++e) {
    int d = threadIdx.x + e * 256;
    out[(size_t)row * 1024 + d] = (x[e] - mu) * inv * ln_g[d] + ln_b[d];
  }
}

// ---------------------------------------------------------------------------
extern "C" void kernel_launch(void* const* d_in, const int* in_sizes, int n_in,
                              void* d_out, int out_size, void* d_ws, size_t ws_size,
                              hipStream_t stream) {
  const float* q   = (const float*)d_in[0];
  const float* k   = (const float*)d_in[1];
  const float* v   = (const float*)d_in[2];
  const float* pe  = (const float*)d_in[3];
  const void*  seg = d_in[4];
  const float* qW  = (const float*)d_in[6];
  const float* kW  = (const float*)d_in[7];
  const float* kb  = (const float*)d_in[8];
  const float* vW  = (const float*)d_in[9];
  const float* vb  = (const float*)d_in[10];
  const float* rwb = (const float*)d_in[11];
  const float* rrb = (const float*)d_in[12];
  const float* rK  = (const float*)d_in[13];
  const float* rsb = (const float*)d_in[14];
  const float* sem = (const float*)d_in[15];
  const float* pW  = (const float*)d_in[16];
  const float* pb  = (const float*)d_in[17];
  const float* lng = (const float*)d_in[18];
  const float* lnb = (const float*)d_in[19];
  float* out = (float*)d_out;

  const size_t MB = 1u << 20;
  char* W = (char*)d_ws;
  ushort_t* qwb  = (ushort_t*)(W + 0 * MB);     // 8 MB
  ushort_t* qrb  = (ushort_t*)(W + 8 * MB);     // 8 MB
  ushort_t* opart = (ushort_t*)(W + 16 * MB);   // 16 MB
  ushort_t* wtq  = (ushort_t*)(W + 32 * MB);
  ushort_t* wtk  = (ushort_t*)(W + 34 * MB);
  ushort_t* wtv  = (ushort_t*)(W + 36 * MB);
  ushort_t* wtr  = (ushort_t*)(W + 38 * MB);
  ushort_t* wtp  = (ushort_t*)(W + 40 * MB);
  ushort_t* av   = (ushort_t*)(W + 42 * MB);    // 8 MB
  ushort_t* kh   = (ushort_t*)(W + 50 * MB);
  ushort_t* vh   = (ushort_t*)(W + 58 * MB);
  ushort_t* rh   = (ushort_t*)(W + 66 * MB);
  unsigned* segw = (unsigned*)(W + 74 * MB);
  float2*   sbp  = (float2*)(W + 74 * MB + 65536);
  float*    ml   = (float*)(W + 75 * MB);
  float*    ao   = (float*)(W + 50 * MB);       // 16MB over kh+vh (dead post-attn)

  seg_extract_kernel<<<dim3(16), dim3(256), 0, stream>>>((const unsigned int*)seg, segw);
  convT_kernel<<<dim3(16, 16, 5), dim3(256), 0, stream>>>(qW, kW, vW, rK, pW,
                                                          wtq, wtk, wtv, wtr, wtp);
  // batched projection GEMMs over fp32 inputs; z==0 fuses qprep
  gemm4_kernel<<<dim3(32, 8, 4), dim3(256), 0, stream>>>(
      q, k, v, pe, wtq, wtk, wtv, wtr, kb, vb, rwb, rrb, rsb, sem,
      qwb, qrb, sbp, kh, vh, rh);

  attn_kernel<<<dim3(2048), dim3(256), 0, stream>>>(qwb, qrb, kh, vh, rh,
                                                    sbp, segw, opart, ml);
  merge_kernel<<<dim3(16384), dim3(256), 0, stream>>>(opart, ml, av);

  gemm_post_kernel<<<dim3(64, 8), dim3(256), 0, stream>>>(av, wtp, pb, ao);
  ln_kernel<<<dim3(4096), dim3(256), 0, stream>>>(q, ao, lng, lnb, out);
}